// Round 1
// baseline (538.760 us; speedup 1.0000x reference)
//
#include <hip/hip_runtime.h>
#include <math.h>

// ---------------- graph prep ----------------

__global__ void k_count(const int* __restrict__ dst, int E, int* __restrict__ cnt) {
    int e = blockIdx.x * blockDim.x + threadIdx.x;
    if (e < E) atomicAdd(&cnt[dst[e]], 1);
}

__global__ void k_dinv(const int* __restrict__ cnt, float* __restrict__ dinv, int n) {
    int i = blockIdx.x * blockDim.x + threadIdx.x;
    if (i < n) dinv[i] = rsqrtf((float)(cnt[i] + 1));  // +1 self loop
}

__global__ __launch_bounds__(1024) void k_scan(const int* __restrict__ cnt,
                                               int* __restrict__ offs, int n) {
    __shared__ int part[1024];
    int t = threadIdx.x;
    int chunk = (n + 1023) >> 10;
    int i0 = t * chunk;
    int i1 = i0 + chunk; if (i1 > n) i1 = n; if (i0 > n) i0 = n;
    int s = 0;
    for (int i = i0; i < i1; ++i) s += cnt[i];
    part[t] = s;
    __syncthreads();
    for (int off = 1; off < 1024; off <<= 1) {
        int v = 0;
        if (t >= off) v = part[t - off];
        __syncthreads();
        if (t >= off) part[t] += v;
        __syncthreads();
    }
    int base = part[t] - s;  // exclusive prefix for this chunk
    for (int i = i0; i < i1; ++i) { offs[i] = base; base += cnt[i]; }
    if (t == 1023) offs[n] = part[1023];
}

__global__ void k_fill(const int* __restrict__ src, const int* __restrict__ dst, int E,
                       const int* __restrict__ offs, int* __restrict__ cursor,
                       const float* __restrict__ dinv,
                       int* __restrict__ csr_src, float* __restrict__ csr_w) {
    int e = blockIdx.x * blockDim.x + threadIdx.x;
    if (e >= E) return;
    int s = src[e], d = dst[e];
    int p = atomicAdd(&cursor[d], 1);
    int idx = offs[d] + p;
    csr_src[idx] = s;
    csr_w[idx] = dinv[s] * dinv[d];
}

__global__ void k_padw(const float* __restrict__ W2, float* __restrict__ Wp) {
    int idx = blockIdx.x * blockDim.x + threadIdx.x;  // 128*64
    if (idx < 128 * 64) {
        int k = idx >> 6, c = idx & 63;
        Wp[idx] = (c < 40) ? W2[k * 40 + c] : 0.f;
    }
}

// ---------------- GEMM: H[n x F] = X[n x 128] @ W[128 x F], F = 64*COLG ----------------
// block: 64 rows x F cols; thread (c_id = tid&15, r_id = tid>>4):
//   rows r_id + 16*i (i<4), cols {4c_id..+3} and (+64 if COLG==2)
template <int COLG>
__global__ __launch_bounds__(256) void k_gemm(const float* __restrict__ X,
                                              const float* __restrict__ W,
                                              float* __restrict__ H, int n) {
    constexpr int F = 64 * COLG;
    __shared__ float4 Xs4[64 * 32];        // 64 rows x 128 k  (32KB)
    __shared__ float4 Ws4[16 * F];         // 64 k x F cols    (16/32KB)
    int tid = threadIdx.x;
    int rbase = blockIdx.x * 64;

    {   // stage X tile (rows are contiguous in global -> flat vector copy)
        const float4* Xg = (const float4*)X;
        for (int t = tid; t < 2048; t += 256) {
            int r = rbase + (t >> 5);
            float4 v = make_float4(0.f, 0.f, 0.f, 0.f);
            if (r < n) v = Xg[rbase * 32 + t];
            Xs4[t] = v;
        }
    }

    int c_id = tid & 15;
    int r_id = tid >> 4;
    float4 acc[4][COLG];
#pragma unroll
    for (int i = 0; i < 4; ++i)
#pragma unroll
        for (int j = 0; j < COLG; ++j) acc[i][j] = make_float4(0.f, 0.f, 0.f, 0.f);

    const float4* Wg = (const float4*)W;
    for (int p = 0; p < 2; ++p) {
        __syncthreads();
        for (int t = tid; t < 16 * F; t += 256)  // 64 k-rows x F cols / 4
            Ws4[t] = Wg[p * 16 * F + t];
        __syncthreads();
#pragma unroll 4
        for (int kl = 0; kl < 64; kl += 4) {
            float4 xv[4];
#pragma unroll
            for (int i = 0; i < 4; ++i)
                xv[i] = Xs4[(r_id + 16 * i) * 32 + p * 16 + (kl >> 2)];
            float4 wv[4][COLG];
#pragma unroll
            for (int t = 0; t < 4; ++t)
#pragma unroll
                for (int j = 0; j < COLG; ++j)
                    wv[t][j] = Ws4[(kl + t) * (F / 4) + c_id + 16 * j];
#pragma unroll
            for (int i = 0; i < 4; ++i) {
                float xs[4] = {xv[i].x, xv[i].y, xv[i].z, xv[i].w};
#pragma unroll
                for (int t = 0; t < 4; ++t)
#pragma unroll
                    for (int j = 0; j < COLG; ++j) {
                        acc[i][j].x = fmaf(xs[t], wv[t][j].x, acc[i][j].x);
                        acc[i][j].y = fmaf(xs[t], wv[t][j].y, acc[i][j].y);
                        acc[i][j].z = fmaf(xs[t], wv[t][j].z, acc[i][j].z);
                        acc[i][j].w = fmaf(xs[t], wv[t][j].w, acc[i][j].w);
                    }
            }
        }
    }
    float4* Hg = (float4*)H;
#pragma unroll
    for (int i = 0; i < 4; ++i) {
        int r = rbase + r_id + 16 * i;
        if (r < n) {
#pragma unroll
            for (int j = 0; j < COLG; ++j)
                Hg[r * (F / 4) + c_id + 16 * j] = acc[i][j];
        }
    }
}

// ---------------- aggregation: out[i] = relu( sum_e norm_e h[src_e] + dinv_i^2 h[i] + b ) ----
// one wave per node; lane holds 2 features (F=128)
__global__ __launch_bounds__(256) void k_agg128(const float* __restrict__ h,
                                                const int* __restrict__ offs,
                                                const int* __restrict__ csr_src,
                                                const float* __restrict__ csr_w,
                                                const float* __restrict__ dinv,
                                                const float* __restrict__ bias,
                                                float* __restrict__ out, int n) {
    int wid = (blockIdx.x * blockDim.x + threadIdx.x) >> 6;
    int lane = threadIdx.x & 63;
    if (wid >= n) return;
    const float2* h2 = (const float2*)h;
    float di = dinv[wid];
    float2 t0 = h2[wid * 64 + lane];
    float2 acc = make_float2(t0.x * di * di, t0.y * di * di);
    int e = offs[wid], e1 = offs[wid + 1];
    // simple 1-deep software pipeline for (s,w)
    int s = 0; float w = 0.f;
    if (e < e1) { s = csr_src[e]; w = csr_w[e]; }
    for (; e < e1; ) {
        float2 v = h2[s * 64 + lane];
        ++e;
        int sn = 0; float wn = 0.f;
        if (e < e1) { sn = csr_src[e]; wn = csr_w[e]; }
        acc.x = fmaf(w, v.x, acc.x);
        acc.y = fmaf(w, v.y, acc.y);
        s = sn; w = wn;
    }
    float2 b = ((const float2*)bias)[lane];
    float2 o = make_float2(fmaxf(acc.x + b.x, 0.f), fmaxf(acc.y + b.y, 0.f));
    ((float2*)out)[wid * 64 + lane] = o;
}

// final layer: F=40 (h padded to 64 cols with exact zeros), fused bias+relu+log_softmax
__global__ __launch_bounds__(256) void k_agg40(const float* __restrict__ hb,
                                               const int* __restrict__ offs,
                                               const int* __restrict__ csr_src,
                                               const float* __restrict__ csr_w,
                                               const float* __restrict__ dinv,
                                               const float* __restrict__ bias,
                                               float* __restrict__ out, int n) {
    int wid = (blockIdx.x * blockDim.x + threadIdx.x) >> 6;
    int lane = threadIdx.x & 63;
    if (wid >= n) return;
    float di = dinv[wid];
    float acc = hb[wid * 64 + lane] * di * di;
    int e = offs[wid], e1 = offs[wid + 1];
    int s = 0; float w = 0.f;
    if (e < e1) { s = csr_src[e]; w = csr_w[e]; }
    for (; e < e1; ) {
        float v = hb[s * 64 + lane];
        ++e;
        int sn = 0; float wn = 0.f;
        if (e < e1) { sn = csr_src[e]; wn = csr_w[e]; }
        acc = fmaf(w, v, acc);
        s = sn; w = wn;
    }
    float v = (lane < 40) ? fmaxf(acc + bias[lane], 0.f) : -INFINITY;
    float m = v;
#pragma unroll
    for (int d = 32; d; d >>= 1) m = fmaxf(m, __shfl_xor(m, d));
    float ex = (lane < 40) ? expf(v - m) : 0.f;
    float ssum = ex;
#pragma unroll
    for (int d = 32; d; d >>= 1) ssum += __shfl_xor(ssum, d);
    if (lane < 40) out[wid * 40 + lane] = v - m - logf(ssum);
}

// ---------------- launch ----------------

extern "C" void kernel_launch(void* const* d_in, const int* in_sizes, int n_in,
                              void* d_out, int out_size, void* d_ws, size_t ws_size,
                              hipStream_t stream) {
    const float* x  = (const float*)d_in[0];
    const int*   ei = (const int*)d_in[1];
    const float* W0 = (const float*)d_in[2];
    const float* b0 = (const float*)d_in[3];
    const float* W1 = (const float*)d_in[4];
    const float* b1 = (const float*)d_in[5];
    const float* W2 = (const float*)d_in[6];
    const float* b2 = (const float*)d_in[7];
    float* out = (float*)d_out;

    int n = in_sizes[0] / 128;
    int E = in_sizes[1] / 2;
    const int* srcv = ei;
    const int* dstv = ei + E;

    char* w = (char*)d_ws;
    auto alloc = [&](size_t bytes) {
        char* p = w;
        w += (bytes + 255) & ~(size_t)255;
        return p;
    };
    int*   cnt    = (int*)alloc((size_t)n * 4);
    int*   cursor = (int*)alloc((size_t)n * 4);
    int*   offs   = (int*)alloc((size_t)(n + 1) * 4);
    float* dinv   = (float*)alloc((size_t)n * 4);
    int*   csr_s  = (int*)alloc((size_t)E * 4);
    float* csr_w  = (float*)alloc((size_t)E * 4);
    float* fA     = (float*)alloc((size_t)n * 128 * 4);
    float* fB     = (float*)alloc((size_t)n * 128 * 4);
    float* h2     = (float*)alloc((size_t)n * 64 * 4);
    float* Wp     = (float*)alloc(128 * 64 * 4);

    hipMemsetAsync(cnt, 0, (size_t)n * 4, stream);
    hipMemsetAsync(cursor, 0, (size_t)n * 4, stream);

    k_count<<<(E + 255) / 256, 256, 0, stream>>>(dstv, E, cnt);
    k_dinv<<<(n + 255) / 256, 256, 0, stream>>>(cnt, dinv, n);
    k_scan<<<1, 1024, 0, stream>>>(cnt, offs, n);
    k_fill<<<(E + 255) / 256, 256, 0, stream>>>(srcv, dstv, E, offs, cursor, dinv, csr_s, csr_w);
    k_padw<<<(128 * 64 + 255) / 256, 256, 0, stream>>>(W2, Wp);

    int gblocks = (n + 63) / 64;
    int ablocks = (n + 3) / 4;

    // layer 0
    k_gemm<2><<<gblocks, 256, 0, stream>>>(x, W0, fA, n);
    k_agg128<<<ablocks, 256, 0, stream>>>(fA, offs, csr_s, csr_w, dinv, b0, fB, n);
    // layer 1
    k_gemm<2><<<gblocks, 256, 0, stream>>>(fB, W1, fA, n);
    k_agg128<<<ablocks, 256, 0, stream>>>(fA, offs, csr_s, csr_w, dinv, b1, fB, n);
    // layer 2 + log_softmax
    k_gemm<1><<<gblocks, 256, 0, stream>>>(fB, Wp, h2, n);
    k_agg40<<<ablocks, 256, 0, stream>>>(h2, offs, csr_s, csr_w, dinv, b2, out, n);
}

// Round 2
// 531.072 us; speedup vs baseline: 1.0145x; 1.0145x over previous
//
#include <hip/hip_runtime.h>
#include <math.h>

typedef unsigned int uint;
typedef unsigned short ushort;

// ---------------- bf16 helpers (RNE pack, shift unpack) ----------------

__device__ inline uint bf16rne(float f) {
    uint u = __float_as_uint(f);
    uint r = ((u >> 16) & 1u) + 0x7fffu;
    return (u + r) >> 16;
}
__device__ inline uint packbf2(float a, float b) {
    return bf16rne(a) | (bf16rne(b) << 16);
}
__device__ inline float unlo(uint v) { return __uint_as_float(v << 16); }
__device__ inline float unhi(uint v) { return __uint_as_float(v & 0xffff0000u); }

// ---------------- graph prep ----------------

__global__ void k_count(const int* __restrict__ dst, int E, int* __restrict__ cnt) {
    int e = blockIdx.x * blockDim.x + threadIdx.x;
    if (e < E) atomicAdd(&cnt[dst[e]], 1);
}

// region allocation via global atomic (order arbitrary — only contiguity matters);
// wave-aggregated by the AMDGPU atomic optimizer. Fuses dinv.
__global__ void k_alloc(const int* __restrict__ cnt, int* __restrict__ offs,
                        int* __restrict__ ends, float* __restrict__ dinv,
                        int* __restrict__ gcur, int n) {
    int i = blockIdx.x * blockDim.x + threadIdx.x;
    if (i >= n) return;
    int c = cnt[i];
    int s = atomicAdd(gcur, c);
    offs[i] = s;
    ends[i] = s + c;
    dinv[i] = rsqrtf((float)(c + 1));  // +1 self loop
}

__global__ void k_fill(const int* __restrict__ src, const int* __restrict__ dst, int E,
                       const int* __restrict__ offs, int* __restrict__ cursor,
                       const float* __restrict__ dinv,
                       int* __restrict__ csr_src, float* __restrict__ csr_w) {
    int e = blockIdx.x * blockDim.x + threadIdx.x;
    if (e >= E) return;
    int s = src[e], d = dst[e];
    int p = atomicAdd(&cursor[d], 1);
    int idx = offs[d] + p;
    csr_src[idx] = s;
    csr_w[idx] = dinv[s] * dinv[d];
}

__global__ void k_padw(const float* __restrict__ W2, float* __restrict__ Wp) {
    int idx = blockIdx.x * blockDim.x + threadIdx.x;  // 128*64
    if (idx < 128 * 64) {
        int k = idx >> 6, c = idx & 63;
        Wp[idx] = (c < 40) ? W2[k * 40 + c] : 0.f;
    }
}

// ---------------- GEMM: Hb[n x F](bf16) = X[n x 128](fp32) @ W[128 x F], F = 64*COLG --------
// block: 64 rows x F cols; thread (c_id = tid&15, r_id = tid>>4):
//   rows r_id + 16*i (i<4), cols {4c_id..+3} and (+64 if COLG==2)
template <int COLG>
__global__ __launch_bounds__(256) void k_gemm(const float* __restrict__ X,
                                              const float* __restrict__ W,
                                              uint* __restrict__ Hb, int n) {
    constexpr int F = 64 * COLG;
    __shared__ float4 Xs4[64 * 32];        // 64 rows x 128 k  (32KB)
    __shared__ float4 Ws4[16 * F];         // 64 k x F cols    (16/32KB)
    int tid = threadIdx.x;
    int rbase = blockIdx.x * 64;

    {   // stage X tile (rows contiguous in global -> flat vector copy)
        const float4* Xg = (const float4*)X;
        for (int t = tid; t < 2048; t += 256) {
            int r = rbase + (t >> 5);
            float4 v = make_float4(0.f, 0.f, 0.f, 0.f);
            if (r < n) v = Xg[rbase * 32 + t];
            Xs4[t] = v;
        }
    }

    int c_id = tid & 15;
    int r_id = tid >> 4;
    float4 acc[4][COLG];
#pragma unroll
    for (int i = 0; i < 4; ++i)
#pragma unroll
        for (int j = 0; j < COLG; ++j) acc[i][j] = make_float4(0.f, 0.f, 0.f, 0.f);

    const float4* Wg = (const float4*)W;
    for (int p = 0; p < 2; ++p) {
        __syncthreads();
        for (int t = tid; t < 16 * F; t += 256)  // 64 k-rows x F cols / 4
            Ws4[t] = Wg[p * 16 * F + t];
        __syncthreads();
#pragma unroll 4
        for (int kl = 0; kl < 64; kl += 4) {
            float4 xv[4];
#pragma unroll
            for (int i = 0; i < 4; ++i)
                xv[i] = Xs4[(r_id + 16 * i) * 32 + p * 16 + (kl >> 2)];
            float4 wv[4][COLG];
#pragma unroll
            for (int t = 0; t < 4; ++t)
#pragma unroll
                for (int j = 0; j < COLG; ++j)
                    wv[t][j] = Ws4[(kl + t) * (F / 4) + c_id + 16 * j];
#pragma unroll
            for (int i = 0; i < 4; ++i) {
                float xs[4] = {xv[i].x, xv[i].y, xv[i].z, xv[i].w};
#pragma unroll
                for (int t = 0; t < 4; ++t)
#pragma unroll
                    for (int j = 0; j < COLG; ++j) {
                        acc[i][j].x = fmaf(xs[t], wv[t][j].x, acc[i][j].x);
                        acc[i][j].y = fmaf(xs[t], wv[t][j].y, acc[i][j].y);
                        acc[i][j].z = fmaf(xs[t], wv[t][j].z, acc[i][j].z);
                        acc[i][j].w = fmaf(xs[t], wv[t][j].w, acc[i][j].w);
                    }
            }
        }
    }
    // epilogue: pack fp32 -> bf16 pairs, 8B stores. Row = F/2 uints.
#pragma unroll
    for (int i = 0; i < 4; ++i) {
        int r = rbase + r_id + 16 * i;
        if (r < n) {
            uint2* row = (uint2*)(Hb + (size_t)r * (F / 2));
#pragma unroll
            for (int j = 0; j < COLG; ++j) {
                float4 a = acc[i][j];
                row[c_id + j * 16] = make_uint2(packbf2(a.x, a.y), packbf2(a.z, a.w));
            }
        }
    }
}

// ---------------- aggregation: y[i] = relu( sum_e w_e h[src_e] + dinv_i^2 h[i] + b ) --------
// one wave per node; lane holds 2 bf16 features (F=128); fp32 accumulate; fp32 out
__global__ __launch_bounds__(256) void k_agg128(const uint* __restrict__ hb,
                                                const int* __restrict__ offs,
                                                const int* __restrict__ ends,
                                                const int* __restrict__ csr_src,
                                                const float* __restrict__ csr_w,
                                                const float* __restrict__ dinv,
                                                const float* __restrict__ bias,
                                                float* __restrict__ out, int n) {
    int wid = (blockIdx.x * blockDim.x + threadIdx.x) >> 6;
    int lane = threadIdx.x & 63;
    if (wid >= n) return;
    float di = dinv[wid];
    uint t0 = hb[(size_t)wid * 64 + lane];
    float2 acc = make_float2(unlo(t0) * di * di, unhi(t0) * di * di);
    int e = offs[wid], e1 = ends[wid];
    // 1-deep pipeline: (s,w) and the gather prefetched one iter ahead
    float w = 0.f;
    uint vcur = 0;
    if (e < e1) {
        int s = csr_src[e];
        w = csr_w[e];
        vcur = hb[(size_t)s * 64 + lane];
    }
    for (; e < e1;) {
        ++e;
        float wn = 0.f;
        uint vn = 0;
        if (e < e1) {
            int sn = csr_src[e];
            wn = csr_w[e];
            vn = hb[(size_t)sn * 64 + lane];
        }
        acc.x = fmaf(w, unlo(vcur), acc.x);
        acc.y = fmaf(w, unhi(vcur), acc.y);
        vcur = vn; w = wn;
    }
    float2 b = ((const float2*)bias)[lane];
    float2 o = make_float2(fmaxf(acc.x + b.x, 0.f), fmaxf(acc.y + b.y, 0.f));
    ((float2*)out)[(size_t)wid * 64 + lane] = o;
}

// final layer: F=40 (h padded to 64 cols with exact zeros, bf16), fused bias+relu+log_softmax
__global__ __launch_bounds__(256) void k_agg40(const ushort* __restrict__ hb,
                                               const int* __restrict__ offs,
                                               const int* __restrict__ ends,
                                               const int* __restrict__ csr_src,
                                               const float* __restrict__ csr_w,
                                               const float* __restrict__ dinv,
                                               const float* __restrict__ bias,
                                               float* __restrict__ out, int n) {
    int wid = (blockIdx.x * blockDim.x + threadIdx.x) >> 6;
    int lane = threadIdx.x & 63;
    if (wid >= n) return;
    float di = dinv[wid];
    float acc = __uint_as_float(((uint)hb[(size_t)wid * 64 + lane]) << 16) * di * di;
    int e = offs[wid], e1 = ends[wid];
    float w = 0.f;
    float vcur = 0.f;
    if (e < e1) {
        int s = csr_src[e];
        w = csr_w[e];
        vcur = __uint_as_float(((uint)hb[(size_t)s * 64 + lane]) << 16);
    }
    for (; e < e1;) {
        ++e;
        float wn = 0.f, vn = 0.f;
        if (e < e1) {
            int sn = csr_src[e];
            wn = csr_w[e];
            vn = __uint_as_float(((uint)hb[(size_t)sn * 64 + lane]) << 16);
        }
        acc = fmaf(w, vcur, acc);
        vcur = vn; w = wn;
    }
    float v = (lane < 40) ? fmaxf(acc + bias[lane], 0.f) : -INFINITY;
    float m = v;
#pragma unroll
    for (int d = 32; d; d >>= 1) m = fmaxf(m, __shfl_xor(m, d));
    float ex = (lane < 40) ? expf(v - m) : 0.f;
    float ssum = ex;
#pragma unroll
    for (int d = 32; d; d >>= 1) ssum += __shfl_xor(ssum, d);
    if (lane < 40) out[wid * 40 + lane] = v - m - logf(ssum);
}

// ---------------- launch ----------------

extern "C" void kernel_launch(void* const* d_in, const int* in_sizes, int n_in,
                              void* d_out, int out_size, void* d_ws, size_t ws_size,
                              hipStream_t stream) {
    const float* x  = (const float*)d_in[0];
    const int*   ei = (const int*)d_in[1];
    const float* W0 = (const float*)d_in[2];
    const float* b0 = (const float*)d_in[3];
    const float* W1 = (const float*)d_in[4];
    const float* b1 = (const float*)d_in[5];
    const float* W2 = (const float*)d_in[6];
    const float* b2 = (const float*)d_in[7];
    float* out = (float*)d_out;

    int n = in_sizes[0] / 128;
    int E = in_sizes[1] / 2;
    const int* srcv = ei;
    const int* dstv = ei + E;

    char* w = (char*)d_ws;
    auto alloc = [&](size_t bytes) {
        char* p = w;
        w += (bytes + 255) & ~(size_t)255;
        return p;
    };
    int*   cnt    = (int*)alloc((size_t)n * 4);
    int*   cursor = (int*)alloc((size_t)n * 4);
    int*   offs   = (int*)alloc((size_t)n * 4);
    int*   ends   = (int*)alloc((size_t)n * 4);
    int*   gcur   = (int*)alloc(4);
    float* dinv   = (float*)alloc((size_t)n * 4);
    int*   csr_s  = (int*)alloc((size_t)E * 4);
    float* csr_w  = (float*)alloc((size_t)E * 4);
    uint*  hbA    = (uint*)alloc((size_t)n * 64 * 4);   // n x 128 bf16
    float* yB     = (float*)alloc((size_t)n * 128 * 4); // n x 128 fp32
    ushort* hbC   = (ushort*)alloc((size_t)n * 64 * 2); // n x 64 bf16
    float* Wp     = (float*)alloc(128 * 64 * 4);

    hipMemsetAsync(cnt, 0, (size_t)n * 4, stream);
    hipMemsetAsync(cursor, 0, (size_t)n * 4, stream);
    hipMemsetAsync(gcur, 0, 4, stream);

    k_count<<<(E + 255) / 256, 256, 0, stream>>>(dstv, E, cnt);
    k_alloc<<<(n + 255) / 256, 256, 0, stream>>>(cnt, offs, ends, dinv, gcur, n);
    k_fill<<<(E + 255) / 256, 256, 0, stream>>>(srcv, dstv, E, offs, cursor, dinv, csr_s, csr_w);
    k_padw<<<(128 * 64 + 255) / 256, 256, 0, stream>>>(W2, Wp);

    int gblocks = (n + 63) / 64;
    int ablocks = (n + 3) / 4;

    // layer 0
    k_gemm<2><<<gblocks, 256, 0, stream>>>(x, W0, hbA, n);
    k_agg128<<<ablocks, 256, 0, stream>>>(hbA, offs, ends, csr_s, csr_w, dinv, b0, yB, n);
    // layer 1
    k_gemm<2><<<gblocks, 256, 0, stream>>>(yB, W1, hbA, n);
    k_agg128<<<ablocks, 256, 0, stream>>>(hbA, offs, ends, csr_s, csr_w, dinv, b1, yB, n);
    // layer 2 + log_softmax
    k_gemm<1><<<gblocks, 256, 0, stream>>>(yB, Wp, (uint*)hbC, n);
    k_agg40<<<ablocks, 256, 0, stream>>>(hbC, offs, ends, csr_s, csr_w, dinv, b2, out, n);
}

// Round 3
// 401.946 us; speedup vs baseline: 1.3404x; 1.3213x over previous
//
#include <hip/hip_runtime.h>
#include <math.h>

typedef unsigned int uint;
typedef unsigned short ushort;

// ---------------- bf16 helpers (RNE pack, shift unpack) ----------------

__device__ inline uint bf16rne(float f) {
    uint u = __float_as_uint(f);
    uint r = ((u >> 16) & 1u) + 0x7fffu;
    return (u + r) >> 16;
}
__device__ inline uint packbf2(float a, float b) {
    return bf16rne(a) | (bf16rne(b) << 16);
}
__device__ inline float unlo(uint v) { return __uint_as_float(v << 16); }
__device__ inline float unhi(uint v) { return __uint_as_float(v & 0xffff0000u); }

// ---------------- graph prep ----------------

__global__ void k_count(const int* __restrict__ dst, int E, int* __restrict__ cnt) {
    int e = blockIdx.x * blockDim.x + threadIdx.x;
    if (e < E) atomicAdd(&cnt[dst[e]], 1);
}

// region allocation via global atomic (order arbitrary — only contiguity matters);
// wave-aggregated by the AMDGPU atomic optimizer. Fuses dinv.
__global__ void k_alloc(const int* __restrict__ cnt, int* __restrict__ offs,
                        int* __restrict__ ends, float* __restrict__ dinv,
                        int* __restrict__ gcur, int n) {
    int i = blockIdx.x * blockDim.x + threadIdx.x;
    if (i >= n) return;
    int c = cnt[i];
    int s = atomicAdd(gcur, c);
    offs[i] = s;
    ends[i] = s + c;
    dinv[i] = rsqrtf((float)(c + 1));  // +1 self loop
}

// csr entry = uint2{ src, bits(w) } — one 8B load per edge in the gather kernels
__global__ void k_fill(const int* __restrict__ src, const int* __restrict__ dst, int E,
                       const int* __restrict__ offs, int* __restrict__ cursor,
                       const float* __restrict__ dinv,
                       uint2* __restrict__ csr) {
    int e = blockIdx.x * blockDim.x + threadIdx.x;
    if (e >= E) return;
    int s = src[e], d = dst[e];
    int p = atomicAdd(&cursor[d], 1);
    int idx = offs[d] + p;
    csr[idx] = make_uint2((uint)s, __float_as_uint(dinv[s] * dinv[d]));
}

__global__ void k_padw(const float* __restrict__ W2, float* __restrict__ Wp) {
    int idx = blockIdx.x * blockDim.x + threadIdx.x;  // 128*64
    if (idx < 128 * 64) {
        int k = idx >> 6, c = idx & 63;
        Wp[idx] = (c < 40) ? W2[k * 40 + c] : 0.f;
    }
}

// ---------------- GEMM: Hb[n x F](bf16) = X[n x 128](fp32) @ W[128 x F], F = 64*COLG --------
template <int COLG>
__global__ __launch_bounds__(256) void k_gemm(const float* __restrict__ X,
                                              const float* __restrict__ W,
                                              uint* __restrict__ Hb, int n) {
    constexpr int F = 64 * COLG;
    __shared__ float4 Xs4[64 * 32];        // 64 rows x 128 k  (32KB)
    __shared__ float4 Ws4[16 * F];         // 64 k x F cols    (16/32KB)
    int tid = threadIdx.x;
    int rbase = blockIdx.x * 64;

    {   // stage X tile (rows contiguous in global -> flat vector copy)
        const float4* Xg = (const float4*)X;
        for (int t = tid; t < 2048; t += 256) {
            int r = rbase + (t >> 5);
            float4 v = make_float4(0.f, 0.f, 0.f, 0.f);
            if (r < n) v = Xg[rbase * 32 + t];
            Xs4[t] = v;
        }
    }

    int c_id = tid & 15;
    int r_id = tid >> 4;
    float4 acc[4][COLG];
#pragma unroll
    for (int i = 0; i < 4; ++i)
#pragma unroll
        for (int j = 0; j < COLG; ++j) acc[i][j] = make_float4(0.f, 0.f, 0.f, 0.f);

    const float4* Wg = (const float4*)W;
    for (int p = 0; p < 2; ++p) {
        __syncthreads();
        for (int t = tid; t < 16 * F; t += 256)  // 64 k-rows x F cols / 4
            Ws4[t] = Wg[p * 16 * F + t];
        __syncthreads();
#pragma unroll 4
        for (int kl = 0; kl < 64; kl += 4) {
            float4 xv[4];
#pragma unroll
            for (int i = 0; i < 4; ++i)
                xv[i] = Xs4[(r_id + 16 * i) * 32 + p * 16 + (kl >> 2)];
            float4 wv[4][COLG];
#pragma unroll
            for (int t = 0; t < 4; ++t)
#pragma unroll
                for (int j = 0; j < COLG; ++j)
                    wv[t][j] = Ws4[(kl + t) * (F / 4) + c_id + 16 * j];
#pragma unroll
            for (int i = 0; i < 4; ++i) {
                float xs[4] = {xv[i].x, xv[i].y, xv[i].z, xv[i].w};
#pragma unroll
                for (int t = 0; t < 4; ++t)
#pragma unroll
                    for (int j = 0; j < COLG; ++j) {
                        acc[i][j].x = fmaf(xs[t], wv[t][j].x, acc[i][j].x);
                        acc[i][j].y = fmaf(xs[t], wv[t][j].y, acc[i][j].y);
                        acc[i][j].z = fmaf(xs[t], wv[t][j].z, acc[i][j].z);
                        acc[i][j].w = fmaf(xs[t], wv[t][j].w, acc[i][j].w);
                    }
            }
        }
    }
    // epilogue: pack fp32 -> bf16 pairs, 8B stores. Row = F/2 uints.
#pragma unroll
    for (int i = 0; i < 4; ++i) {
        int r = rbase + r_id + 16 * i;
        if (r < n) {
            uint2* row = (uint2*)(Hb + (size_t)r * (F / 2));
#pragma unroll
            for (int j = 0; j < COLG; ++j) {
                float4 a = acc[i][j];
                row[c_id + j * 16] = make_uint2(packbf2(a.x, a.y), packbf2(a.z, a.w));
            }
        }
    }
}

// ---------------- aggregation helpers: chunked, software-pipelined gather ----------------

template <int K>
__device__ inline void load_pairsK(const uint2* __restrict__ csr, int eb, int e1, uint2* p) {
#pragma unroll
    for (int j = 0; j < K; ++j) {
        uint2 t = csr[eb + j];            // csr padded by 4K entries -> never OOB
        bool ok = (eb + j) < e1;          // wave-uniform
        p[j].x = ok ? t.x : 0u;           // masked: row 0 (cache-hot broadcast)
        p[j].y = ok ? t.y : 0u;           // masked: w = 0 -> exact zero contribution
    }
}

// ---------------- aggregation: y[i] = relu( sum_e w_e h[src_e] + dinv_i^2 h[i] + b ) --------
// one wave per node; lane holds 2 bf16 features (F=128); fp32 accumulate; fp32 out.
// K=8 gathers in flight, pipelined one chunk ahead -> latency-hiding.
__global__ __launch_bounds__(256) void k_agg128(const uint* __restrict__ hb,
                                                const int* __restrict__ offs,
                                                const int* __restrict__ ends,
                                                const uint2* __restrict__ csr,
                                                const float* __restrict__ dinv,
                                                const float* __restrict__ bias,
                                                float* __restrict__ out, int n) {
    constexpr int K = 8;
    int wid = (blockIdx.x * blockDim.x + threadIdx.x) >> 6;
    int lane = threadIdx.x & 63;
    if (wid >= n) return;
    float di = dinv[wid];
    uint t0 = hb[((size_t)wid << 6) + lane];
    float2 acc = make_float2(unlo(t0) * di * di, unhi(t0) * di * di);
    int e0 = offs[wid], e1 = ends[wid];
    int nchunk = (e1 - e0 + K - 1) / K;

    uint2 Pa[K], Pb[K];
    uint Ga[K], Gb[K];

    auto gatherK = [&](const uint2* p, uint* g) {
#pragma unroll
        for (int j = 0; j < K; ++j) g[j] = hb[((size_t)p[j].x << 6) + lane];
    };
    auto fmaK = [&](const uint2* p, const uint* g) {
#pragma unroll
        for (int j = 0; j < K; ++j) {
            float w = __uint_as_float(p[j].y);
            acc.x = fmaf(w, unlo(g[j]), acc.x);
            acc.y = fmaf(w, unhi(g[j]), acc.y);
        }
    };

    if (nchunk > 0) {
        load_pairsK<K>(csr, e0, e1, Pa);
        gatherK(Pa, Ga);
        load_pairsK<K>(csr, e0 + K, e1, Pb);
        int c = 0;
        while (true) {
            gatherK(Pb, Gb);   // chunk c+1 (pairs pre-loaded)
            fmaK(Pa, Ga);      // chunk c (gathers issued an iter ago)
            if (++c >= nchunk) break;
            load_pairsK<K>(csr, e0 + (c + 1) * K, e1, Pa);
            gatherK(Pa, Ga);   // chunk c+1
            fmaK(Pb, Gb);      // chunk c
            if (++c >= nchunk) break;
            load_pairsK<K>(csr, e0 + (c + 1) * K, e1, Pb);
        }
    }

    float2 b = ((const float2*)bias)[lane];
    float2 o = make_float2(fmaxf(acc.x + b.x, 0.f), fmaxf(acc.y + b.y, 0.f));
    ((float2*)out)[((size_t)wid << 6) + lane] = o;
}

// final layer: F=40 (h padded to 64 cols with exact zeros, bf16), fused bias+relu+log_softmax
__global__ __launch_bounds__(256) void k_agg40(const ushort* __restrict__ hb,
                                               const int* __restrict__ offs,
                                               const int* __restrict__ ends,
                                               const uint2* __restrict__ csr,
                                               const float* __restrict__ dinv,
                                               const float* __restrict__ bias,
                                               float* __restrict__ out, int n) {
    constexpr int K = 8;
    int wid = (blockIdx.x * blockDim.x + threadIdx.x) >> 6;
    int lane = threadIdx.x & 63;
    if (wid >= n) return;
    float di = dinv[wid];
    float acc = __uint_as_float(((uint)hb[((size_t)wid << 6) + lane]) << 16) * di * di;
    int e0 = offs[wid], e1 = ends[wid];
    int nchunk = (e1 - e0 + K - 1) / K;

    uint2 Pa[K], Pb[K];
    uint Ga[K], Gb[K];

    auto gatherK = [&](const uint2* p, uint* g) {
#pragma unroll
        for (int j = 0; j < K; ++j) g[j] = (uint)hb[((size_t)p[j].x << 6) + lane];
    };
    auto fmaK = [&](const uint2* p, const uint* g) {
#pragma unroll
        for (int j = 0; j < K; ++j) {
            float w = __uint_as_float(p[j].y);
            acc = fmaf(w, __uint_as_float(g[j] << 16), acc);
        }
    };

    if (nchunk > 0) {
        load_pairsK<K>(csr, e0, e1, Pa);
        gatherK(Pa, Ga);
        load_pairsK<K>(csr, e0 + K, e1, Pb);
        int c = 0;
        while (true) {
            gatherK(Pb, Gb);
            fmaK(Pa, Ga);
            if (++c >= nchunk) break;
            load_pairsK<K>(csr, e0 + (c + 1) * K, e1, Pa);
            gatherK(Pa, Ga);
            fmaK(Pb, Gb);
            if (++c >= nchunk) break;
            load_pairsK<K>(csr, e0 + (c + 1) * K, e1, Pb);
        }
    }

    float v = (lane < 40) ? fmaxf(acc + bias[lane], 0.f) : -INFINITY;
    float m = v;
#pragma unroll
    for (int d = 32; d; d >>= 1) m = fmaxf(m, __shfl_xor(m, d));
    float ex = (lane < 40) ? expf(v - m) : 0.f;
    float ssum = ex;
#pragma unroll
    for (int d = 32; d; d >>= 1) ssum += __shfl_xor(ssum, d);
    if (lane < 40) out[wid * 40 + lane] = v - m - logf(ssum);
}

// ---------------- launch ----------------

extern "C" void kernel_launch(void* const* d_in, const int* in_sizes, int n_in,
                              void* d_out, int out_size, void* d_ws, size_t ws_size,
                              hipStream_t stream) {
    const float* x  = (const float*)d_in[0];
    const int*   ei = (const int*)d_in[1];
    const float* W0 = (const float*)d_in[2];
    const float* b0 = (const float*)d_in[3];
    const float* W1 = (const float*)d_in[4];
    const float* b1 = (const float*)d_in[5];
    const float* W2 = (const float*)d_in[6];
    const float* b2 = (const float*)d_in[7];
    float* out = (float*)d_out;

    int n = in_sizes[0] / 128;
    int E = in_sizes[1] / 2;
    const int* srcv = ei;
    const int* dstv = ei + E;

    char* w = (char*)d_ws;
    auto alloc = [&](size_t bytes) {
        char* p = w;
        w += (bytes + 255) & ~(size_t)255;
        return p;
    };
    int*   cnt    = (int*)alloc((size_t)n * 4);
    int*   cursor = (int*)alloc((size_t)n * 4);
    int*   offs   = (int*)alloc((size_t)n * 4);
    int*   ends   = (int*)alloc((size_t)n * 4);
    int*   gcur   = (int*)alloc(4);
    float* dinv   = (float*)alloc((size_t)n * 4);
    uint2* csr    = (uint2*)alloc(((size_t)E + 32) * 8);   // padded: pipelined loads overrun ≤ 4K
    uint*  hbA    = (uint*)alloc((size_t)n * 64 * 4);      // n x 128 bf16
    float* yB     = (float*)alloc((size_t)n * 128 * 4);    // n x 128 fp32
    ushort* hbC   = (ushort*)alloc((size_t)n * 64 * 2);    // n x 64 bf16
    float* Wp     = (float*)alloc(128 * 64 * 4);

    hipMemsetAsync(cnt, 0, (size_t)n * 4, stream);
    hipMemsetAsync(cursor, 0, (size_t)n * 4, stream);
    hipMemsetAsync(gcur, 0, 4, stream);

    k_count<<<(E + 255) / 256, 256, 0, stream>>>(dstv, E, cnt);
    k_alloc<<<(n + 255) / 256, 256, 0, stream>>>(cnt, offs, ends, dinv, gcur, n);
    k_fill<<<(E + 255) / 256, 256, 0, stream>>>(srcv, dstv, E, offs, cursor, dinv, csr);
    k_padw<<<(128 * 64 + 255) / 256, 256, 0, stream>>>(W2, Wp);

    int gblocks = (n + 63) / 64;
    int ablocks = (n + 3) / 4;

    // layer 0
    k_gemm<2><<<gblocks, 256, 0, stream>>>(x, W0, hbA, n);
    k_agg128<<<ablocks, 256, 0, stream>>>(hbA, offs, ends, csr, dinv, b0, yB, n);
    // layer 1
    k_gemm<2><<<gblocks, 256, 0, stream>>>(yB, W1, hbA, n);
    k_agg128<<<ablocks, 256, 0, stream>>>(hbA, offs, ends, csr, dinv, b1, yB, n);
    // layer 2 + log_softmax
    k_gemm<1><<<gblocks, 256, 0, stream>>>(yB, Wp, (uint*)hbC, n);
    k_agg40<<<ablocks, 256, 0, stream>>>(hbC, offs, ends, csr, dinv, b2, out, n);
}

// Round 4
// 367.293 us; speedup vs baseline: 1.4668x; 1.0943x over previous
//
#include <hip/hip_runtime.h>
#include <math.h>

typedef unsigned int uint;
typedef unsigned short ushort;

typedef __bf16 bf16x8 __attribute__((ext_vector_type(8)));
typedef float f32x4 __attribute__((ext_vector_type(4)));

// ---------------- bf16 helpers (RNE pack, shift unpack) ----------------

__device__ inline uint bf16rne(float f) {
    uint u = __float_as_uint(f);
    uint r = ((u >> 16) & 1u) + 0x7fffu;
    return (u + r) >> 16;
}
__device__ inline uint packbf2(float a, float b) {
    return bf16rne(a) | (bf16rne(b) << 16);
}
__device__ inline float unlo(uint v) { return __uint_as_float(v << 16); }
__device__ inline float unhi(uint v) { return __uint_as_float(v & 0xffff0000u); }

// ---------------- graph prep ----------------

__global__ void k_count(const int* __restrict__ dst, int E, int* __restrict__ cnt) {
    int e = blockIdx.x * blockDim.x + threadIdx.x;
    if (e < E) atomicAdd(&cnt[dst[e]], 1);
}

__global__ void k_alloc(const int* __restrict__ cnt, int* __restrict__ offs,
                        int* __restrict__ ends, float* __restrict__ dinv,
                        int* __restrict__ gcur, int n) {
    int i = blockIdx.x * blockDim.x + threadIdx.x;
    if (i >= n) return;
    int c = cnt[i];
    int s = atomicAdd(gcur, c);
    offs[i] = s;
    ends[i] = s + c;
    dinv[i] = rsqrtf((float)(c + 1));  // +1 self loop
}

// csr entry = uint2{ src, bits(w) }
__global__ void k_fill(const int* __restrict__ src, const int* __restrict__ dst, int E,
                       const int* __restrict__ offs, int* __restrict__ cursor,
                       const float* __restrict__ dinv,
                       uint2* __restrict__ csr) {
    int e = blockIdx.x * blockDim.x + threadIdx.x;
    if (e >= E) return;
    int s = src[e], d = dst[e];
    int p = atomicAdd(&cursor[d], 1);
    int idx = offs[d] + p;
    csr[idx] = make_uint2((uint)s, __float_as_uint(dinv[s] * dinv[d]));
}

// x fp32 -> bf16 (packed pairs)
__global__ void k_convx(const float4* __restrict__ X, uint2* __restrict__ Xb, int n4) {
    int i = blockIdx.x * blockDim.x + threadIdx.x;
    if (i < n4) {
        float4 v = X[i];
        Xb[i] = make_uint2(packbf2(v.x, v.y), packbf2(v.z, v.w));
    }
}

// W[K=128 x F] fp32 -> WT[F x 128] bf16
__global__ void k_wtrans(const float* __restrict__ W, ushort* __restrict__ WT, int F) {
    int idx = blockIdx.x * blockDim.x + threadIdx.x;  // over 128*F
    if (idx < 128 * F) {
        int k = idx / F, c = idx - k * F;
        WT[c * 128 + k] = (ushort)bf16rne(W[idx]);
    }
}

// W2[128 x 40] fp32 -> WT2[64 x 128] bf16, cols 40..63 zero
__global__ void k_padwt(const float* __restrict__ W2, ushort* __restrict__ WT2) {
    int idx = blockIdx.x * blockDim.x + threadIdx.x;  // 64*128
    if (idx < 64 * 128) {
        int c = idx >> 7, k = idx & 127;
        WT2[idx] = (c < 40) ? (ushort)bf16rne(W2[k * 40 + c]) : (ushort)0;
    }
}

// ---------------- MFMA GEMM: Hb[n x F](bf16) = Xb[n x 128](bf16) @ W, WT = W^T[F x 128] ----
// wave = 16 rows x F cols; A frag A[m=lane&15][k=quad*8+j] (16B global loads);
// B frag = WT rows (B^T pattern); D: col=lane&15, row=quad*4+reg. No LDS.
template <int F>
__global__ __launch_bounds__(256) void k_mgemm(const __bf16* __restrict__ Xb,
                                               const __bf16* __restrict__ WT,
                                               ushort* __restrict__ Hb, int n) {
    constexpr int NT = F / 16;  // 16-col tiles
    int lane = threadIdx.x & 63;
    int wv = threadIdx.x >> 6;
    int rbase = blockIdx.x * 64 + wv * 16;
    if (rbase >= n) return;  // n % 16 == 0: strips fully valid or fully absent
    int m = lane & 15, quad = lane >> 4;

    const __bf16* xrow = Xb + (size_t)(rbase + m) * 128 + quad * 8;
    bf16x8 a[4];
#pragma unroll
    for (int ks = 0; ks < 4; ++ks) a[ks] = *(const bf16x8*)(xrow + ks * 32);

    f32x4 acc[NT];
#pragma unroll
    for (int t = 0; t < NT; ++t) acc[t] = (f32x4){0.f, 0.f, 0.f, 0.f};

#pragma unroll
    for (int t = 0; t < NT; ++t) {
        const __bf16* wrow = WT + (size_t)(t * 16 + m) * 128 + quad * 8;
#pragma unroll
        for (int ks = 0; ks < 4; ++ks) {
            bf16x8 b = *(const bf16x8*)(wrow + ks * 32);
            acc[t] = __builtin_amdgcn_mfma_f32_16x16x32_bf16(a[ks], b, acc[t], 0, 0, 0);
        }
    }

#pragma unroll
    for (int t = 0; t < NT; ++t) {
#pragma unroll
        for (int r = 0; r < 4; ++r) {
            int row = rbase + quad * 4 + r;
            Hb[(size_t)row * F + t * 16 + m] = (ushort)bf16rne(acc[t][r]);
        }
    }
}

// ---------------- aggregation helpers: chunked, software-pipelined gather ----------------

template <int K>
__device__ inline void load_pairsK(const uint2* __restrict__ csr, int eb, int e1, uint2* p) {
#pragma unroll
    for (int j = 0; j < K; ++j) {
        uint2 t = csr[eb + j];            // csr padded -> never OOB
        bool ok = (eb + j) < e1;          // wave-uniform
        p[j].x = ok ? t.x : 0u;           // masked: row 0 (cache-hot broadcast)
        p[j].y = ok ? t.y : 0u;           // masked: w = 0 -> exact zero contribution
    }
}

// ---------------- aggregation: y[i] = relu( sum_e w_e h[src_e] + dinv_i^2 h[i] + b ) --------
// one wave per node; lane = 2 bf16 features (F=128); fp32 accumulate; bf16 packed out.
__global__ __launch_bounds__(256) void k_agg128(const uint* __restrict__ hb,
                                                const int* __restrict__ offs,
                                                const int* __restrict__ ends,
                                                const uint2* __restrict__ csr,
                                                const float* __restrict__ dinv,
                                                const float* __restrict__ bias,
                                                uint* __restrict__ out, int n) {
    constexpr int K = 8;
    int wid = (blockIdx.x * blockDim.x + threadIdx.x) >> 6;
    int lane = threadIdx.x & 63;
    if (wid >= n) return;
    float di = dinv[wid];
    uint t0 = hb[((size_t)wid << 6) + lane];
    float2 acc = make_float2(unlo(t0) * di * di, unhi(t0) * di * di);
    int e0 = offs[wid], e1 = ends[wid];
    int nchunk = (e1 - e0 + K - 1) / K;

    uint2 Pa[K], Pb[K];
    uint Ga[K], Gb[K];

    auto gatherK = [&](const uint2* p, uint* g) {
#pragma unroll
        for (int j = 0; j < K; ++j) g[j] = hb[((size_t)p[j].x << 6) + lane];
    };
    auto fmaK = [&](const uint2* p, const uint* g) {
#pragma unroll
        for (int j = 0; j < K; ++j) {
            float w = __uint_as_float(p[j].y);
            acc.x = fmaf(w, unlo(g[j]), acc.x);
            acc.y = fmaf(w, unhi(g[j]), acc.y);
        }
    };

    if (nchunk > 0) {
        load_pairsK<K>(csr, e0, e1, Pa);
        gatherK(Pa, Ga);
        load_pairsK<K>(csr, e0 + K, e1, Pb);
        int c = 0;
        while (true) {
            gatherK(Pb, Gb);   // chunk c+1 (pairs pre-loaded)
            fmaK(Pa, Ga);      // chunk c (gathers issued an iter ago)
            if (++c >= nchunk) break;
            load_pairsK<K>(csr, e0 + (c + 1) * K, e1, Pa);
            gatherK(Pa, Ga);
            fmaK(Pb, Gb);
            if (++c >= nchunk) break;
            load_pairsK<K>(csr, e0 + (c + 1) * K, e1, Pb);
        }
    }

    float2 b = ((const float2*)bias)[lane];
    out[((size_t)wid << 6) + lane] =
        packbf2(fmaxf(acc.x + b.x, 0.f), fmaxf(acc.y + b.y, 0.f));
}

// final layer: F=40 (padded to 64 with exact zeros, bf16), fused bias+relu+log_softmax
__global__ __launch_bounds__(256) void k_agg40(const ushort* __restrict__ hb,
                                               const int* __restrict__ offs,
                                               const int* __restrict__ ends,
                                               const uint2* __restrict__ csr,
                                               const float* __restrict__ dinv,
                                               const float* __restrict__ bias,
                                               float* __restrict__ out, int n) {
    constexpr int K = 8;
    int wid = (blockIdx.x * blockDim.x + threadIdx.x) >> 6;
    int lane = threadIdx.x & 63;
    if (wid >= n) return;
    float di = dinv[wid];
    float acc = __uint_as_float(((uint)hb[((size_t)wid << 6) + lane]) << 16) * di * di;
    int e0 = offs[wid], e1 = ends[wid];
    int nchunk = (e1 - e0 + K - 1) / K;

    uint2 Pa[K], Pb[K];
    uint Ga[K], Gb[K];

    auto gatherK = [&](const uint2* p, uint* g) {
#pragma unroll
        for (int j = 0; j < K; ++j) g[j] = (uint)hb[((size_t)p[j].x << 6) + lane];
    };
    auto fmaK = [&](const uint2* p, const uint* g) {
#pragma unroll
        for (int j = 0; j < K; ++j) {
            float w = __uint_as_float(p[j].y);
            acc = fmaf(w, __uint_as_float(g[j] << 16), acc);
        }
    };

    if (nchunk > 0) {
        load_pairsK<K>(csr, e0, e1, Pa);
        gatherK(Pa, Ga);
        load_pairsK<K>(csr, e0 + K, e1, Pb);
        int c = 0;
        while (true) {
            gatherK(Pb, Gb);
            fmaK(Pa, Ga);
            if (++c >= nchunk) break;
            load_pairsK<K>(csr, e0 + (c + 1) * K, e1, Pa);
            gatherK(Pa, Ga);
            fmaK(Pb, Gb);
            if (++c >= nchunk) break;
            load_pairsK<K>(csr, e0 + (c + 1) * K, e1, Pb);
        }
    }

    float v = (lane < 40) ? fmaxf(acc + bias[lane], 0.f) : -INFINITY;
    float m = v;
#pragma unroll
    for (int d = 32; d; d >>= 1) m = fmaxf(m, __shfl_xor(m, d));
    float ex = (lane < 40) ? expf(v - m) : 0.f;
    float ssum = ex;
#pragma unroll
    for (int d = 32; d; d >>= 1) ssum += __shfl_xor(ssum, d);
    if (lane < 40) out[wid * 40 + lane] = v - m - logf(ssum);
}

// ---------------- launch ----------------

extern "C" void kernel_launch(void* const* d_in, const int* in_sizes, int n_in,
                              void* d_out, int out_size, void* d_ws, size_t ws_size,
                              hipStream_t stream) {
    const float* x  = (const float*)d_in[0];
    const int*   ei = (const int*)d_in[1];
    const float* W0 = (const float*)d_in[2];
    const float* b0 = (const float*)d_in[3];
    const float* W1 = (const float*)d_in[4];
    const float* b1 = (const float*)d_in[5];
    const float* W2 = (const float*)d_in[6];
    const float* b2 = (const float*)d_in[7];
    float* out = (float*)d_out;

    int n = in_sizes[0] / 128;
    int E = in_sizes[1] / 2;
    const int* srcv = ei;
    const int* dstv = ei + E;

    char* w = (char*)d_ws;
    auto alloc = [&](size_t bytes) {
        char* p = w;
        w += (bytes + 255) & ~(size_t)255;
        return p;
    };
    int*    cnt    = (int*)alloc((size_t)n * 4);
    int*    cursor = (int*)alloc((size_t)n * 4);
    int*    offs   = (int*)alloc((size_t)n * 4);
    int*    ends   = (int*)alloc((size_t)n * 4);
    int*    gcur   = (int*)alloc(4);
    float*  dinv   = (float*)alloc((size_t)n * 4);
    uint2*  csr    = (uint2*)alloc(((size_t)E + 32) * 8);  // padded: pipeline overrun < 16
    uint*   xb     = (uint*)alloc((size_t)n * 64 * 4);     // n x 128 bf16; reused as agg out
    uint*   hA     = (uint*)alloc((size_t)n * 64 * 4);     // n x 128 bf16 (gemm out)
    ushort* hC     = (ushort*)alloc((size_t)n * 64 * 2);   // n x 64 bf16
    ushort* WT0    = (ushort*)alloc(128 * 128 * 2);
    ushort* WT1    = (ushort*)alloc(128 * 128 * 2);
    ushort* WT2    = (ushort*)alloc(64 * 128 * 2);

    hipMemsetAsync(cnt, 0, (size_t)n * 4, stream);
    hipMemsetAsync(cursor, 0, (size_t)n * 4, stream);
    hipMemsetAsync(gcur, 0, 4, stream);

    k_count<<<(E + 255) / 256, 256, 0, stream>>>(dstv, E, cnt);
    k_alloc<<<(n + 255) / 256, 256, 0, stream>>>(cnt, offs, ends, dinv, gcur, n);
    k_fill<<<(E + 255) / 256, 256, 0, stream>>>(srcv, dstv, E, offs, cursor, dinv, csr);
    k_convx<<<(n * 32 + 255) / 256, 256, 0, stream>>>((const float4*)x, (uint2*)xb, n * 32);
    k_wtrans<<<(128 * 128 + 255) / 256, 256, 0, stream>>>(W0, WT0, 128);
    k_wtrans<<<(128 * 128 + 255) / 256, 256, 0, stream>>>(W1, WT1, 128);
    k_padwt<<<(64 * 128 + 255) / 256, 256, 0, stream>>>(W2, WT2);

    int gblocks = (n + 63) / 64;
    int ablocks = (n + 3) / 4;

    // layer 0
    k_mgemm<128><<<gblocks, 256, 0, stream>>>((const __bf16*)xb, (const __bf16*)WT0,
                                              (ushort*)hA, n);
    k_agg128<<<ablocks, 256, 0, stream>>>(hA, offs, ends, csr, dinv, b0, xb, n);
    // layer 1 (agg out reuses xb)
    k_mgemm<128><<<gblocks, 256, 0, stream>>>((const __bf16*)xb, (const __bf16*)WT1,
                                              (ushort*)hA, n);
    k_agg128<<<ablocks, 256, 0, stream>>>(hA, offs, ends, csr, dinv, b1, xb, n);
    // layer 2 + log_softmax
    k_mgemm<64><<<gblocks, 256, 0, stream>>>((const __bf16*)xb, (const __bf16*)WT2, hC, n);
    k_agg40<<<ablocks, 256, 0, stream>>>(hC, offs, ends, csr, dinv, b2, out, n);
}